// Round 1
// baseline (2456.682 us; speedup 1.0000x reference)
//
#include <hip/hip_runtime.h>

#define NNODES 100000
#define NEDGES 640000
#define HDIM 128
#define CDIM 16

typedef __attribute__((ext_vector_type(8))) short bf16x8;
typedef __attribute__((ext_vector_type(4))) float f32x4;

__device__ __forceinline__ unsigned short f2bf(float f) {
    unsigned int u = __float_as_uint(f);
    unsigned int r = (u + 0x7fffu + ((u >> 16) & 1u)) >> 16;   // RNE
    return (unsigned short)r;
}

__global__ void deg_kernel(const int* __restrict__ dst, float* __restrict__ deg) {
    int e = blockIdx.x * blockDim.x + threadIdx.x;
    if (e < NEDGES) atomicAdd(&deg[dst[e]], 1.0f);
}

__global__ void inv_kernel(float* __restrict__ deg) {
    int i = blockIdx.x * blockDim.x + threadIdx.x;
    if (i < NNODES) deg[i] = 1.0f / fmaxf(deg[i], 1.0f);
}

// one edge handled by 32 threads; each thread: float4 gather + 4 f32 atomics
__global__ void scatter_kernel(const float* __restrict__ feat, const int* __restrict__ src,
                               const int* __restrict__ dst, float* __restrict__ msg) {
    int t = blockIdx.x * blockDim.x + threadIdx.x;
    int e = t >> 5;
    int c = t & 31;
    if (e >= NEDGES) return;
    int s = src[e];
    int d = dst[e];
    float4 v = reinterpret_cast<const float4*>(feat)[s * 32 + c];
    float* p = msg + ((size_t)d * HDIM + c * 4);
    atomicAdd(p + 0, v.x);
    atomicAdd(p + 1, v.y);
    atomicAdd(p + 2, v.z);
    atomicAdd(p + 3, v.w);
}

// out[row][col] = (RELU?)( [msg*inv | feat](row,:) @ [Wl;Wr](:,colbase+col) + bias[col] )
// A is N x 256 (bf16, staged), W is 256 x OUTW. Block covers 64 rows x NCOL cols.
// LDS layout: KP=256 bf16 per row, 16B chunks XOR-swizzled by (row&7) to kill
// the 512B-stride bank aliasing on ds_read_b128 fragment reads.
template<int NCOL, int OUTW, bool RELU>
__global__ __launch_bounds__(256) void gemm_kernel(
    const float* __restrict__ msg, const float* __restrict__ inv,
    const float* __restrict__ feat, const float* __restrict__ Wl,
    const float* __restrict__ Wr, const float* __restrict__ bias,
    float* __restrict__ out, int ntiles)
{
    __shared__ unsigned short At[64 * 256];
    __shared__ unsigned short Wt[NCOL * 256];

    const int tid = threadIdx.x;
    const int colbase = blockIdx.y * NCOL;

    // ---- stage weights once per block: Wt[n][k] = Wcat[k][colbase+n], swizzled ----
    for (int idx = tid; idx < 128 * NCOL; idx += 256) {
        int k = idx / NCOL;            // NCOL is 64 or 16 -> shifts
        int n = idx % NCOL;
        float vl = Wl[k * OUTW + colbase + n];
        float vr = Wr[k * OUTW + colbase + n];
        int ck = k >> 3;
        Wt[n * 256 + ((ck ^ (n & 7)) << 3) + (k & 7)] = f2bf(vl);
        int k2 = k + 128;
        int ck2 = k2 >> 3;
        Wt[n * 256 + ((ck2 ^ (n & 7)) << 3) + (k2 & 7)] = f2bf(vr);
    }

    const int wave = tid >> 6;
    const int lane = tid & 63;
    const int lm = lane & 15;       // m (A) / n (B) / col (C)
    const int lq = lane >> 4;       // quad

    for (int tile = blockIdx.x; tile < ntiles; tile += gridDim.x) {
        int row0 = tile * 64;
        __syncthreads();            // At free of previous readers

        // ---- stage A-tile: 64 rows x 64 float4 units (32 from msg*inv, 32 from feat) ----
        #pragma unroll
        for (int i = 0; i < 16; ++i) {
            int idx = tid + i * 256;        // 0..4095
            int r = idx >> 6;
            int q = idx & 63;
            int row = row0 + r;
            float4 v = make_float4(0.f, 0.f, 0.f, 0.f);
            int kpos;
            if (q < 32) {
                kpos = q * 4;
                if (row < NNODES) {
                    v = reinterpret_cast<const float4*>(msg)[(size_t)row * 32 + q];
                    float s = inv[row];
                    v.x *= s; v.y *= s; v.z *= s; v.w *= s;
                }
            } else {
                kpos = 128 + (q - 32) * 4;
                if (row < NNODES)
                    v = reinterpret_cast<const float4*>(feat)[(size_t)row * 32 + (q - 32)];
            }
            int ck = kpos >> 3;
            int off = r * 256 + ((ck ^ (r & 7)) << 3) + (kpos & 7);
            ushort4 b;
            b.x = f2bf(v.x); b.y = f2bf(v.y); b.z = f2bf(v.z); b.w = f2bf(v.w);
            *reinterpret_cast<ushort4*>(&At[off]) = b;
        }
        __syncthreads();

        // ---- MFMA: wave w covers rows [w*16, w*16+16), all NCOL cols ----
        constexpr int CT = NCOL / 16;
        f32x4 acc[CT];
        #pragma unroll
        for (int c = 0; c < CT; ++c) acc[c] = (f32x4)(0.0f);

        const int arow = wave * 16 + lm;
        const int arh = arow & 7;
        #pragma unroll
        for (int kt = 0; kt < 8; ++kt) {
            int c = kt * 4 + lq;    // 16B chunk index along K
            bf16x8 a = *reinterpret_cast<const bf16x8*>(&At[arow * 256 + ((c ^ arh) << 3)]);
            #pragma unroll
            for (int ct = 0; ct < CT; ++ct) {
                int n = ct * 16 + lm;
                bf16x8 b = *reinterpret_cast<const bf16x8*>(&Wt[n * 256 + ((c ^ (n & 7)) << 3)]);
                acc[ct] = __builtin_amdgcn_mfma_f32_16x16x32_bf16(a, b, acc[ct], 0, 0, 0);
            }
        }

        // ---- epilogue: C[row=quad*4+i][col=lm] ----
        #pragma unroll
        for (int ct = 0; ct < CT; ++ct) {
            int col = colbase + ct * 16 + lm;
            float bv = bias[col];
            #pragma unroll
            for (int i = 0; i < 4; ++i) {
                int row = row0 + wave * 16 + lq * 4 + i;
                if (row < NNODES) {
                    float v = acc[ct][i] + bv;
                    if (RELU) v = fmaxf(v, 0.0f);
                    out[(size_t)row * OUTW + col] = v;
                }
            }
        }
    }
}

extern "C" void kernel_launch(void* const* d_in, const int* in_sizes, int n_in,
                              void* d_out, int out_size, void* d_ws, size_t ws_size,
                              hipStream_t stream) {
    const float* x   = (const float*)d_in[0];
    const int*   ei  = (const int*)d_in[1];
    const float* W1l = (const float*)d_in[2];
    const float* W1r = (const float*)d_in[3];
    const float* b1  = (const float*)d_in[4];
    const float* W2l = (const float*)d_in[5];
    const float* W2r = (const float*)d_in[6];
    const float* b2  = (const float*)d_in[7];
    float* out = (float*)d_out;

    const int* src = ei;
    const int* dst = ei + NEDGES;

    // workspace: deg/inv (padded) | msg (N*128) | h (N*128)  ~= 103 MB
    float* deg = (float*)d_ws;
    float* msg = deg + 100352;                       // 128-aligned pad past N
    float* h   = msg + (size_t)NNODES * HDIM;

    hipMemsetAsync(deg, 0, 100352 * sizeof(float), stream);
    hipMemsetAsync(msg, 0, (size_t)NNODES * HDIM * sizeof(float), stream);

    deg_kernel<<<(NEDGES + 255) / 256, 256, 0, stream>>>(dst, deg);
    inv_kernel<<<(NNODES + 255) / 256, 256, 0, stream>>>(deg);

    scatter_kernel<<<(NEDGES * 32) / 256, 256, 0, stream>>>(x, src, dst, msg);

    int ntiles = (NNODES + 63) / 64;
    gemm_kernel<64, 128, true><<<dim3(256, 2), 256, 0, stream>>>(
        msg, deg, x, W1l, W1r, b1, h, ntiles);

    hipMemsetAsync(msg, 0, (size_t)NNODES * HDIM * sizeof(float), stream);
    scatter_kernel<<<(NEDGES * 32) / 256, 256, 0, stream>>>(h, src, dst, msg);

    gemm_kernel<16, 16, false><<<dim3(256, 1), 256, 0, stream>>>(
        msg, deg, h, W2l, W2r, b2, out, ntiles);
}

// Round 2
// 604.801 us; speedup vs baseline: 4.0620x; 4.0620x over previous
//
#include <hip/hip_runtime.h>

#define NNODES 100000
#define NEDGES 640000
#define HDIM 128
#define CDIM 16

typedef __attribute__((ext_vector_type(8))) short bf16x8;
typedef __attribute__((ext_vector_type(4))) float f32x4;

__device__ __forceinline__ unsigned short f2bf(float f) {
    unsigned int u = __float_as_uint(f);
    unsigned int r = (u + 0x7fffu + ((u >> 16) & 1u)) >> 16;   // RNE
    return (unsigned short)r;
}
__device__ __forceinline__ float bf2f(unsigned short s) {
    return __uint_as_float(((unsigned int)s) << 16);
}

__global__ void hist_kernel(const int* __restrict__ dst, int* __restrict__ cnt) {
    int e = blockIdx.x * blockDim.x + threadIdx.x;
    if (e < NEDGES) atomicAdd(&cnt[dst[e]], 1);
}

// single block, 1024 threads: exclusive scan of counts -> offs & cursor,
// and inv-degree (float) written over the counts array.
__global__ __launch_bounds__(1024) void scan_kernel(
    int* __restrict__ cnt_inv, int* __restrict__ offs, int* __restrict__ cursor)
{
    __shared__ int sbuf[2][1024];
    const int t = threadIdx.x;
    const int CS = (NNODES + 1023) / 1024;          // 98
    const int base = t * CS;
    const int lim = min(base + CS, NNODES);
    int sum = 0;
    for (int i = base; i < lim; ++i) sum += cnt_inv[i];
    sbuf[0][t] = sum;
    __syncthreads();
    int cur = 0;
    for (int d = 1; d < 1024; d <<= 1) {
        int v = sbuf[cur][t];
        if (t >= d) v += sbuf[cur][t - d];
        sbuf[cur ^ 1][t] = v;
        __syncthreads();
        cur ^= 1;
    }
    const int incl = sbuf[cur][t];
    int off = incl - sum;                            // exclusive
    for (int i = base; i < lim; ++i) {
        int c = cnt_inv[i];
        offs[i] = off;
        cursor[i] = off;
        cnt_inv[i] = __float_as_int(1.0f / fmaxf((float)c, 1.0f));
        off += c;
    }
    if (t == 1023) offs[NNODES] = sbuf[cur][1023];
}

__global__ void bin_kernel(const int* __restrict__ src, const int* __restrict__ dst,
                           int* __restrict__ cursor, int* __restrict__ ebuf) {
    int e = blockIdx.x * blockDim.x + threadIdx.x;
    if (e >= NEDGES) return;
    int p = atomicAdd(&cursor[dst[e]], 1);
    ebuf[p] = src[e];
}

// 32 lanes per node; lane c accumulates features [4c,4c+4). No atomics.
template<bool SRC_BF16>
__global__ __launch_bounds__(256) void gather_kernel(
    const void* __restrict__ feat, const int* __restrict__ offs,
    const int* __restrict__ ebuf, const float* __restrict__ inv,
    unsigned short* __restrict__ agg)
{
    int t = blockIdx.x * blockDim.x + threadIdx.x;
    int node = t >> 5;
    int c = t & 31;
    if (node >= NNODES) return;
    int beg = offs[node];
    int end = offs[node + 1];
    float ax = 0.f, ay = 0.f, az = 0.f, aw = 0.f;
    for (int j = beg; j < end; ++j) {
        int s = ebuf[j];
        if (SRC_BF16) {
            ushort4 u = reinterpret_cast<const ushort4*>(feat)[s * 32 + c];
            ax += bf2f(u.x); ay += bf2f(u.y); az += bf2f(u.z); aw += bf2f(u.w);
        } else {
            float4 v = reinterpret_cast<const float4*>(feat)[s * 32 + c];
            ax += v.x; ay += v.y; az += v.z; aw += v.w;
        }
    }
    float sc = inv[node];
    ushort4 r;
    r.x = f2bf(ax * sc); r.y = f2bf(ay * sc); r.z = f2bf(az * sc); r.w = f2bf(aw * sc);
    reinterpret_cast<ushort4*>(agg)[node * 32 + c] = r;
}

// out[row][col] = (RELU?)( [agg | feat](row,:) @ [Wl;Wr](:,colbase+col) + bias[col] )
// A: N x 256 bf16 staged in LDS, 16B chunks XOR-swizzled by (row&7).
template<int NCOL, int OUTW, bool RELU, bool FEAT_BF16, bool OUT_BF16>
__global__ __launch_bounds__(256) void gemm_kernel(
    const unsigned short* __restrict__ agg, const void* __restrict__ feat,
    const float* __restrict__ Wl, const float* __restrict__ Wr,
    const float* __restrict__ bias, void* __restrict__ out, int ntiles)
{
    __shared__ alignas(16) unsigned short At[64 * 256];
    __shared__ alignas(16) unsigned short Wt[NCOL * 256];

    const int tid = threadIdx.x;
    const int colbase = blockIdx.y * NCOL;

    // stage weights once: Wt[n][k] = Wcat[k][colbase+n], swizzled
    for (int idx = tid; idx < 128 * NCOL; idx += 256) {
        int k = idx / NCOL;
        int n = idx % NCOL;
        float vl = Wl[k * OUTW + colbase + n];
        float vr = Wr[k * OUTW + colbase + n];
        int ck = k >> 3;
        Wt[n * 256 + ((ck ^ (n & 7)) << 3) + (k & 7)] = f2bf(vl);
        int k2 = k + 128;
        int ck2 = k2 >> 3;
        Wt[n * 256 + ((ck2 ^ (n & 7)) << 3) + (k2 & 7)] = f2bf(vr);
    }

    const int wave = tid >> 6;
    const int lane = tid & 63;
    const int lm = lane & 15;
    const int lq = lane >> 4;

    for (int tile = blockIdx.x; tile < ntiles; tile += gridDim.x) {
        int row0 = tile * 64;
        __syncthreads();

        // ---- A-tile stage: agg half (bf16, direct 16B copies) ----
        #pragma unroll
        for (int i = 0; i < 4; ++i) {
            int idx = tid + i * 256;            // 0..1023
            int r = idx >> 4;
            int ch = idx & 15;                  // 16B chunk, kpos = ch*8
            int row = row0 + r;
            uint4 v = make_uint4(0u, 0u, 0u, 0u);
            if (row < NNODES) v = reinterpret_cast<const uint4*>(agg)[(size_t)row * 16 + ch];
            *reinterpret_cast<uint4*>(&At[r * 256 + ((ch ^ (r & 7)) << 3)]) = v;
        }
        // ---- A-tile stage: feat half (kpos 128..255) ----
        if (FEAT_BF16) {
            #pragma unroll
            for (int i = 0; i < 4; ++i) {
                int idx = tid + i * 256;
                int r = idx >> 4;
                int ch = idx & 15;
                int row = row0 + r;
                uint4 v = make_uint4(0u, 0u, 0u, 0u);
                if (row < NNODES) v = reinterpret_cast<const uint4*>(feat)[(size_t)row * 16 + ch];
                int ck = 16 + ch;
                *reinterpret_cast<uint4*>(&At[r * 256 + ((ck ^ (r & 7)) << 3)]) = v;
            }
        } else {
            #pragma unroll
            for (int i = 0; i < 8; ++i) {
                int idx = tid + i * 256;        // 0..2047
                int r = idx >> 5;
                int u = idx & 31;               // float4 unit, kpos = 128 + u*4
                int row = row0 + r;
                float4 v = make_float4(0.f, 0.f, 0.f, 0.f);
                if (row < NNODES) v = reinterpret_cast<const float4*>(feat)[(size_t)row * 32 + u];
                int kpos = 128 + u * 4;
                int ck = kpos >> 3;
                int off = r * 256 + ((ck ^ (r & 7)) << 3) + (kpos & 7);
                ushort4 b;
                b.x = f2bf(v.x); b.y = f2bf(v.y); b.z = f2bf(v.z); b.w = f2bf(v.w);
                *reinterpret_cast<ushort4*>(&At[off]) = b;
            }
        }
        __syncthreads();

        // ---- MFMA ----
        constexpr int CT = NCOL / 16;
        f32x4 acc[CT];
        #pragma unroll
        for (int c = 0; c < CT; ++c) acc[c] = (f32x4)(0.0f);

        const int arow = wave * 16 + lm;
        const int arh = arow & 7;
        #pragma unroll
        for (int kt = 0; kt < 8; ++kt) {
            int c = kt * 4 + lq;
            bf16x8 a = *reinterpret_cast<const bf16x8*>(&At[arow * 256 + ((c ^ arh) << 3)]);
            #pragma unroll
            for (int ct = 0; ct < CT; ++ct) {
                int n = ct * 16 + lm;
                bf16x8 b = *reinterpret_cast<const bf16x8*>(&Wt[n * 256 + ((c ^ (n & 7)) << 3)]);
                acc[ct] = __builtin_amdgcn_mfma_f32_16x16x32_bf16(a, b, acc[ct], 0, 0, 0);
            }
        }

        // ---- epilogue: C[row=quad*4+i][col=lm] ----
        #pragma unroll
        for (int ct = 0; ct < CT; ++ct) {
            int col = colbase + ct * 16 + lm;
            float bv = bias[col];
            #pragma unroll
            for (int i = 0; i < 4; ++i) {
                int row = row0 + wave * 16 + lq * 4 + i;
                if (row < NNODES) {
                    float v = acc[ct][i] + bv;
                    if (RELU) v = fmaxf(v, 0.0f);
                    if (OUT_BF16)
                        ((unsigned short*)out)[(size_t)row * OUTW + col] = f2bf(v);
                    else
                        ((float*)out)[(size_t)row * OUTW + col] = v;
                }
            }
        }
    }
}

extern "C" void kernel_launch(void* const* d_in, const int* in_sizes, int n_in,
                              void* d_out, int out_size, void* d_ws, size_t ws_size,
                              hipStream_t stream) {
    const float* x   = (const float*)d_in[0];
    const int*   ei  = (const int*)d_in[1];
    const float* W1l = (const float*)d_in[2];
    const float* W1r = (const float*)d_in[3];
    const float* b1  = (const float*)d_in[4];
    const float* W2l = (const float*)d_in[5];
    const float* W2r = (const float*)d_in[6];
    const float* b2  = (const float*)d_in[7];
    float* out = (float*)d_out;

    const int* src = ei;
    const int* dst = ei + NEDGES;

    // workspace layout (ints/shorts, 16B aligned chunks)
    const int NP = 100352;                          // N padded to 128
    int* cnt_inv = (int*)d_ws;                      // counts -> inv-deg (float bits)
    int* offs    = cnt_inv + NP;                    // N+1 used
    int* cursor  = offs + NP;
    int* ebuf    = cursor + NP;                     // E ints
    unsigned short* agg = (unsigned short*)(ebuf + ((NEDGES + 3) & ~3));
    unsigned short* h   = agg + (size_t)NNODES * HDIM;

    hipMemsetAsync(cnt_inv, 0, NP * sizeof(int), stream);

    hist_kernel<<<(NEDGES + 255) / 256, 256, 0, stream>>>(dst, cnt_inv);
    scan_kernel<<<1, 1024, 0, stream>>>(cnt_inv, offs, cursor);
    bin_kernel<<<(NEDGES + 255) / 256, 256, 0, stream>>>(src, dst, cursor, ebuf);

    const float* inv = (const float*)cnt_inv;
    int ntiles = (NNODES + 63) / 64;

    // layer 1
    gather_kernel<false><<<(NNODES * 32) / 256, 256, 0, stream>>>(x, offs, ebuf, inv, agg);
    gemm_kernel<64, 128, true, false, true><<<dim3(256, 2), 256, 0, stream>>>(
        agg, x, W1l, W1r, b1, h, ntiles);

    // layer 2
    gather_kernel<true><<<(NNODES * 32) / 256, 256, 0, stream>>>(h, offs, ebuf, inv, agg);
    gemm_kernel<16, 16, false, true, false><<<dim3(256, 1), 256, 0, stream>>>(
        agg, h, W2l, W2r, b2, out, ntiles);
}

// Round 3
// 336.044 us; speedup vs baseline: 7.3106x; 1.7998x over previous
//
#include <hip/hip_runtime.h>

#define NNODES 100000
#define NEDGES 640000
#define HDIM 128
#define CDIM 16
#define NP 100352           // NNODES padded to multiple of 1024

typedef __attribute__((ext_vector_type(8))) short bf16x8;
typedef __attribute__((ext_vector_type(4))) float f32x4;

__device__ __forceinline__ unsigned short f2bf(float f) {
    unsigned int u = __float_as_uint(f);
    unsigned int r = (u + 0x7fffu + ((u >> 16) & 1u)) >> 16;   // RNE
    return (unsigned short)r;
}
__device__ __forceinline__ float bf2f(unsigned short s) {
    return __uint_as_float(((unsigned int)s) << 16);
}

__global__ void hist_kernel(const int* __restrict__ dst, int* __restrict__ cnt) {
    int e = blockIdx.x * blockDim.x + threadIdx.x;
    if (e < NEDGES) atomicAdd(&cnt[dst[e]], 1);
}

// ---- phase 1: per-block (1024-element) sums ----
__global__ __launch_bounds__(256) void bsum_kernel(const int* __restrict__ cnt,
                                                   int* __restrict__ bsum) {
    __shared__ int ws[4];
    int t = threadIdx.x;
    int4 v = reinterpret_cast<const int4*>(cnt)[blockIdx.x * 256 + t];
    int s = v.x + v.y + v.z + v.w;
    #pragma unroll
    for (int d = 32; d > 0; d >>= 1) s += __shfl_down(s, d);
    if ((t & 63) == 0) ws[t >> 6] = s;
    __syncthreads();
    if (t == 0) bsum[blockIdx.x] = ws[0] + ws[1] + ws[2] + ws[3];
}

// ---- phase 2: exclusive scan of 98 block sums (single tiny block) ----
__global__ __launch_bounds__(128) void bscan_kernel(int* __restrict__ bsum) {
    __shared__ int tmp;
    int t = threadIdx.x;
    int v = (t < NP / 1024) ? bsum[t] : 0;
    int s = v;
    int lane = t & 63;
    #pragma unroll
    for (int d = 1; d < 64; d <<= 1) {
        int u = __shfl_up(s, d);
        if (lane >= d) s += u;
    }
    if (t == 63) tmp = s;
    __syncthreads();
    if (t >= 64) s += tmp;
    if (t < NP / 1024) bsum[t] = s - v;          // exclusive
}

// ---- phase 3: intra-block exclusive scan + base; write offs/cursor/inv ----
__global__ __launch_bounds__(256) void offs_kernel(int* __restrict__ cnt_inv,
                                                   const int* __restrict__ bsum,
                                                   int* __restrict__ offs,
                                                   int* __restrict__ cursor) {
    __shared__ int wsum[4];
    int t = threadIdx.x;
    int gi = blockIdx.x * 256 + t;
    int4 c = reinterpret_cast<const int4*>(cnt_inv)[gi];
    int s0 = c.x, s1 = s0 + c.y, s2 = s1 + c.z, s3 = s2 + c.w;
    int s = s3;
    int lane = t & 63;
    #pragma unroll
    for (int d = 1; d < 64; d <<= 1) {
        int u = __shfl_up(s, d);
        if (lane >= d) s += u;
    }
    if (lane == 63) wsum[t >> 6] = s;
    __syncthreads();
    int w = t >> 6;
    int wbase = 0;
    if (w > 0) wbase = wsum[0];
    if (w > 1) wbase += wsum[1];
    if (w > 2) wbase += wsum[2];
    int base = bsum[blockIdx.x] + wbase + (s - s3);   // exclusive thread base
    int4 o;
    o.x = base; o.y = base + s0; o.z = base + s1; o.w = base + s2;
    reinterpret_cast<int4*>(offs)[gi] = o;
    reinterpret_cast<int4*>(cursor)[gi] = o;
    int4 iv;
    iv.x = __float_as_int(1.0f / fmaxf((float)c.x, 1.0f));
    iv.y = __float_as_int(1.0f / fmaxf((float)c.y, 1.0f));
    iv.z = __float_as_int(1.0f / fmaxf((float)c.z, 1.0f));
    iv.w = __float_as_int(1.0f / fmaxf((float)c.w, 1.0f));
    reinterpret_cast<int4*>(cnt_inv)[gi] = iv;
    if (gi == 0) offs[NNODES] = NEDGES;   // redundant with scan value; explicit for safety
}

__global__ void bin_kernel(const int* __restrict__ src, const int* __restrict__ dst,
                           int* __restrict__ cursor, int* __restrict__ ebuf) {
    int e = blockIdx.x * blockDim.x + threadIdx.x;
    if (e >= NEDGES) return;
    int p = atomicAdd(&cursor[dst[e]], 1);
    ebuf[p] = src[e];
}

// 32 lanes per node; lane c accumulates features [4c,4c+4). No atomics.
template<bool SRC_BF16>
__global__ __launch_bounds__(256) void gather_kernel(
    const void* __restrict__ feat, const int* __restrict__ offs,
    const int* __restrict__ ebuf, const float* __restrict__ inv,
    unsigned short* __restrict__ agg)
{
    int t = blockIdx.x * blockDim.x + threadIdx.x;
    int node = t >> 5;
    int c = t & 31;
    if (node >= NNODES) return;
    int beg = offs[node];
    int end = offs[node + 1];
    float ax = 0.f, ay = 0.f, az = 0.f, aw = 0.f;
    for (int j = beg; j < end; ++j) {
        int s = ebuf[j];
        if (SRC_BF16) {
            ushort4 u = reinterpret_cast<const ushort4*>(feat)[s * 32 + c];
            ax += bf2f(u.x); ay += bf2f(u.y); az += bf2f(u.z); aw += bf2f(u.w);
        } else {
            float4 v = reinterpret_cast<const float4*>(feat)[s * 32 + c];
            ax += v.x; ay += v.y; az += v.z; aw += v.w;
        }
    }
    float sc = inv[node];
    ushort4 r;
    r.x = f2bf(ax * sc); r.y = f2bf(ay * sc); r.z = f2bf(az * sc); r.w = f2bf(aw * sc);
    reinterpret_cast<ushort4*>(agg)[node * 32 + c] = r;
}

// out[row][col] = (RELU?)( [agg | feat](row,:) @ [Wl;Wr](:,colbase+col) + bias[col] )
// A: N x 256 bf16 staged in LDS, 16B chunks XOR-swizzled by (row&7).
template<int NCOL, int OUTW, bool RELU, bool FEAT_BF16, bool OUT_BF16>
__global__ __launch_bounds__(256) void gemm_kernel(
    const unsigned short* __restrict__ agg, const void* __restrict__ feat,
    const float* __restrict__ Wl, const float* __restrict__ Wr,
    const float* __restrict__ bias, void* __restrict__ out, int ntiles)
{
    __shared__ alignas(16) unsigned short At[64 * 256];
    __shared__ alignas(16) unsigned short Wt[NCOL * 256];

    const int tid = threadIdx.x;
    const int colbase = blockIdx.y * NCOL;

    // stage weights once: Wt[n][k] = Wcat[k][colbase+n], swizzled
    for (int idx = tid; idx < 128 * NCOL; idx += 256) {
        int k = idx / NCOL;
        int n = idx % NCOL;
        float vl = Wl[k * OUTW + colbase + n];
        float vr = Wr[k * OUTW + colbase + n];
        int ck = k >> 3;
        Wt[n * 256 + ((ck ^ (n & 7)) << 3) + (k & 7)] = f2bf(vl);
        int k2 = k + 128;
        int ck2 = k2 >> 3;
        Wt[n * 256 + ((ck2 ^ (n & 7)) << 3) + (k2 & 7)] = f2bf(vr);
    }

    const int wave = tid >> 6;
    const int lane = tid & 63;
    const int lm = lane & 15;
    const int lq = lane >> 4;

    for (int tile = blockIdx.x; tile < ntiles; tile += gridDim.x) {
        int row0 = tile * 64;
        __syncthreads();

        // ---- A-tile stage: agg half (bf16, direct 16B copies) ----
        #pragma unroll
        for (int i = 0; i < 4; ++i) {
            int idx = tid + i * 256;            // 0..1023
            int r = idx >> 4;
            int ch = idx & 15;                  // 16B chunk, kpos = ch*8
            int row = row0 + r;
            uint4 v = make_uint4(0u, 0u, 0u, 0u);
            if (row < NNODES) v = reinterpret_cast<const uint4*>(agg)[(size_t)row * 16 + ch];
            *reinterpret_cast<uint4*>(&At[r * 256 + ((ch ^ (r & 7)) << 3)]) = v;
        }
        // ---- A-tile stage: feat half (kpos 128..255) ----
        if (FEAT_BF16) {
            #pragma unroll
            for (int i = 0; i < 4; ++i) {
                int idx = tid + i * 256;
                int r = idx >> 4;
                int ch = idx & 15;
                int row = row0 + r;
                uint4 v = make_uint4(0u, 0u, 0u, 0u);
                if (row < NNODES) v = reinterpret_cast<const uint4*>(feat)[(size_t)row * 16 + ch];
                int ck = 16 + ch;
                *reinterpret_cast<uint4*>(&At[r * 256 + ((ck ^ (r & 7)) << 3)]) = v;
            }
        } else {
            #pragma unroll
            for (int i = 0; i < 8; ++i) {
                int idx = tid + i * 256;        // 0..2047
                int r = idx >> 5;
                int u = idx & 31;               // float4 unit, kpos = 128 + u*4
                int row = row0 + r;
                float4 v = make_float4(0.f, 0.f, 0.f, 0.f);
                if (row < NNODES) v = reinterpret_cast<const float4*>(feat)[(size_t)row * 32 + u];
                int kpos = 128 + u * 4;
                int ck = kpos >> 3;
                int off = r * 256 + ((ck ^ (r & 7)) << 3) + (kpos & 7);
                ushort4 b;
                b.x = f2bf(v.x); b.y = f2bf(v.y); b.z = f2bf(v.z); b.w = f2bf(v.w);
                *reinterpret_cast<ushort4*>(&At[off]) = b;
            }
        }
        __syncthreads();

        // ---- MFMA ----
        constexpr int CT = NCOL / 16;
        f32x4 acc[CT];
        #pragma unroll
        for (int c = 0; c < CT; ++c) acc[c] = (f32x4)(0.0f);

        const int arow = wave * 16 + lm;
        const int arh = arow & 7;
        #pragma unroll
        for (int kt = 0; kt < 8; ++kt) {
            int c = kt * 4 + lq;
            bf16x8 a = *reinterpret_cast<const bf16x8*>(&At[arow * 256 + ((c ^ arh) << 3)]);
            #pragma unroll
            for (int ct = 0; ct < CT; ++ct) {
                int n = ct * 16 + lm;
                bf16x8 b = *reinterpret_cast<const bf16x8*>(&Wt[n * 256 + ((c ^ (n & 7)) << 3)]);
                acc[ct] = __builtin_amdgcn_mfma_f32_16x16x32_bf16(a, b, acc[ct], 0, 0, 0);
            }
        }

        // ---- epilogue: C[row=quad*4+i][col=lm] ----
        #pragma unroll
        for (int ct = 0; ct < CT; ++ct) {
            int col = colbase + ct * 16 + lm;
            float bv = bias[col];
            #pragma unroll
            for (int i = 0; i < 4; ++i) {
                int row = row0 + wave * 16 + lq * 4 + i;
                if (row < NNODES) {
                    float v = acc[ct][i] + bv;
                    if (RELU) v = fmaxf(v, 0.0f);
                    if (OUT_BF16)
                        ((unsigned short*)out)[(size_t)row * OUTW + col] = f2bf(v);
                    else
                        ((float*)out)[(size_t)row * OUTW + col] = v;
                }
            }
        }
    }
}

extern "C" void kernel_launch(void* const* d_in, const int* in_sizes, int n_in,
                              void* d_out, int out_size, void* d_ws, size_t ws_size,
                              hipStream_t stream) {
    const float* x   = (const float*)d_in[0];
    const int*   ei  = (const int*)d_in[1];
    const float* W1l = (const float*)d_in[2];
    const float* W1r = (const float*)d_in[3];
    const float* b1  = (const float*)d_in[4];
    const float* W2l = (const float*)d_in[5];
    const float* W2r = (const float*)d_in[6];
    const float* b2  = (const float*)d_in[7];
    float* out = (float*)d_out;

    const int* src = ei;
    const int* dst = ei + NEDGES;

    // workspace layout
    int* cnt_inv = (int*)d_ws;                      // NP ints: counts -> inv-deg bits
    int* offs    = cnt_inv + NP;                    // NP ints (N+1 used)
    int* cursor  = offs + NP;                       // NP ints
    int* bsum    = cursor + NP;                     // NP/1024 ints (pad to 128)
    int* ebuf    = bsum + 128;                      // E ints
    unsigned short* agg = (unsigned short*)(ebuf + ((NEDGES + 3) & ~3));
    unsigned short* h   = agg + (size_t)NNODES * HDIM;

    hipMemsetAsync(cnt_inv, 0, NP * sizeof(int), stream);

    hist_kernel<<<(NEDGES + 255) / 256, 256, 0, stream>>>(dst, cnt_inv);
    bsum_kernel<<<NP / 1024, 256, 0, stream>>>(cnt_inv, bsum);
    bscan_kernel<<<1, 128, 0, stream>>>(bsum);
    offs_kernel<<<NP / 1024, 256, 0, stream>>>(cnt_inv, bsum, offs, cursor);
    bin_kernel<<<(NEDGES + 255) / 256, 256, 0, stream>>>(src, dst, cursor, ebuf);

    const float* inv = (const float*)cnt_inv;
    int ntiles = (NNODES + 63) / 64;

    // layer 1
    gather_kernel<false><<<(NNODES * 32) / 256, 256, 0, stream>>>(x, offs, ebuf, inv, agg);
    gemm_kernel<64, 128, true, false, true><<<dim3(256, 2), 256, 0, stream>>>(
        agg, x, W1l, W1r, b1, h, ntiles);

    // layer 2
    gather_kernel<true><<<(NNODES * 32) / 256, 256, 0, stream>>>(h, offs, ebuf, inv, agg);
    gemm_kernel<16, 16, false, true, false><<<dim3(256, 1), 256, 0, stream>>>(
        agg, h, W2l, W2r, b2, out, ntiles);
}

// Round 4
// 268.493 us; speedup vs baseline: 9.1499x; 1.2516x over previous
//
#include <hip/hip_runtime.h>

#define NNODES 100000
#define NEDGES 640000
#define HDIM 128
#define CDIM 16
#define NP 100352           // NNODES padded to multiple of 1024

typedef __attribute__((ext_vector_type(8))) short bf16x8;
typedef __attribute__((ext_vector_type(4))) float f32x4;

__device__ __forceinline__ unsigned short f2bf(float f) {
    unsigned int u = __float_as_uint(f);
    unsigned int r = (u + 0x7fffu + ((u >> 16) & 1u)) >> 16;   // RNE
    return (unsigned short)r;
}
__device__ __forceinline__ float bf2f(unsigned short s) {
    return __uint_as_float(((unsigned int)s) << 16);
}

__global__ void hist_kernel(const int* __restrict__ dst, int* __restrict__ cnt) {
    int e = blockIdx.x * blockDim.x + threadIdx.x;
    if (e < NEDGES) atomicAdd(&cnt[dst[e]], 1);
}

// x (f32) -> xb (bf16), N*128 elements
__global__ __launch_bounds__(256) void cvt_kernel(const float* __restrict__ x,
                                                  unsigned short* __restrict__ xb) {
    int i = blockIdx.x * blockDim.x + threadIdx.x;   // float4 unit
    if (i >= NNODES * 32) return;
    float4 v = reinterpret_cast<const float4*>(x)[i];
    ushort4 r;
    r.x = f2bf(v.x); r.y = f2bf(v.y); r.z = f2bf(v.z); r.w = f2bf(v.w);
    reinterpret_cast<ushort4*>(xb)[i] = r;
}

// ---- phase 1: per-block (1024-element) sums ----
__global__ __launch_bounds__(256) void bsum_kernel(const int* __restrict__ cnt,
                                                   int* __restrict__ bsum) {
    __shared__ int ws[4];
    int t = threadIdx.x;
    int4 v = reinterpret_cast<const int4*>(cnt)[blockIdx.x * 256 + t];
    int s = v.x + v.y + v.z + v.w;
    #pragma unroll
    for (int d = 32; d > 0; d >>= 1) s += __shfl_down(s, d);
    if ((t & 63) == 0) ws[t >> 6] = s;
    __syncthreads();
    if (t == 0) bsum[blockIdx.x] = ws[0] + ws[1] + ws[2] + ws[3];
}

// ---- phase 2: exclusive scan of block sums (single tiny block) ----
__global__ __launch_bounds__(128) void bscan_kernel(int* __restrict__ bsum) {
    __shared__ int tmp;
    int t = threadIdx.x;
    int v = (t < NP / 1024) ? bsum[t] : 0;
    int s = v;
    int lane = t & 63;
    #pragma unroll
    for (int d = 1; d < 64; d <<= 1) {
        int u = __shfl_up(s, d);
        if (lane >= d) s += u;
    }
    if (t == 63) tmp = s;
    __syncthreads();
    if (t >= 64) s += tmp;
    if (t < NP / 1024) bsum[t] = s - v;          // exclusive
}

// ---- phase 3: intra-block exclusive scan + base; write offs/cursor/inv ----
__global__ __launch_bounds__(256) void offs_kernel(int* __restrict__ cnt_inv,
                                                   const int* __restrict__ bsum,
                                                   int* __restrict__ offs,
                                                   int* __restrict__ cursor) {
    __shared__ int wsum[4];
    int t = threadIdx.x;
    int gi = blockIdx.x * 256 + t;
    int4 c = reinterpret_cast<const int4*>(cnt_inv)[gi];
    int s0 = c.x, s1 = s0 + c.y, s2 = s1 + c.z, s3 = s2 + c.w;
    int s = s3;
    int lane = t & 63;
    #pragma unroll
    for (int d = 1; d < 64; d <<= 1) {
        int u = __shfl_up(s, d);
        if (lane >= d) s += u;
    }
    if (lane == 63) wsum[t >> 6] = s;
    __syncthreads();
    int w = t >> 6;
    int wbase = 0;
    if (w > 0) wbase = wsum[0];
    if (w > 1) wbase += wsum[1];
    if (w > 2) wbase += wsum[2];
    int base = bsum[blockIdx.x] + wbase + (s - s3);
    int4 o;
    o.x = base; o.y = base + s0; o.z = base + s1; o.w = base + s2;
    reinterpret_cast<int4*>(offs)[gi] = o;
    reinterpret_cast<int4*>(cursor)[gi] = o;
    int4 iv;
    iv.x = __float_as_int(1.0f / fmaxf((float)c.x, 1.0f));
    iv.y = __float_as_int(1.0f / fmaxf((float)c.y, 1.0f));
    iv.z = __float_as_int(1.0f / fmaxf((float)c.z, 1.0f));
    iv.w = __float_as_int(1.0f / fmaxf((float)c.w, 1.0f));
    reinterpret_cast<int4*>(cnt_inv)[gi] = iv;
    if (gi == 0) offs[NNODES] = NEDGES;
}

__global__ void bin_kernel(const int* __restrict__ src, const int* __restrict__ dst,
                           int* __restrict__ cursor, int* __restrict__ ebuf) {
    int e = blockIdx.x * blockDim.x + threadIdx.x;
    if (e >= NEDGES) return;
    int p = atomicAdd(&cursor[dst[e]], 1);
    ebuf[p] = src[e];
}

// layer-1 aggregation: 16 lanes per node, 8 bf16 (16B) per lane. No atomics.
__global__ __launch_bounds__(256) void gather1_kernel(
    const unsigned short* __restrict__ xb, const int* __restrict__ offs,
    const int* __restrict__ ebuf, const float* __restrict__ inv,
    unsigned short* __restrict__ agg)
{
    int t = blockIdx.x * blockDim.x + threadIdx.x;
    int node = t >> 4;
    int c = t & 15;
    if (node >= NNODES) return;
    int beg = offs[node];
    int end = offs[node + 1];
    float a0 = 0.f, a1 = 0.f, a2 = 0.f, a3 = 0.f, a4 = 0.f, a5 = 0.f, a6 = 0.f, a7 = 0.f;
    int j = beg;
    for (; j + 1 < end; j += 2) {
        int s0 = ebuf[j], s1 = ebuf[j + 1];
        uint4 u = reinterpret_cast<const uint4*>(xb)[s0 * 16 + c];
        uint4 v = reinterpret_cast<const uint4*>(xb)[s1 * 16 + c];
        a0 += bf2f(u.x & 0xffff) + bf2f(v.x & 0xffff);
        a1 += bf2f(u.x >> 16)    + bf2f(v.x >> 16);
        a2 += bf2f(u.y & 0xffff) + bf2f(v.y & 0xffff);
        a3 += bf2f(u.y >> 16)    + bf2f(v.y >> 16);
        a4 += bf2f(u.z & 0xffff) + bf2f(v.z & 0xffff);
        a5 += bf2f(u.z >> 16)    + bf2f(v.z >> 16);
        a6 += bf2f(u.w & 0xffff) + bf2f(v.w & 0xffff);
        a7 += bf2f(u.w >> 16)    + bf2f(v.w >> 16);
    }
    if (j < end) {
        int s0 = ebuf[j];
        uint4 u = reinterpret_cast<const uint4*>(xb)[s0 * 16 + c];
        a0 += bf2f(u.x & 0xffff); a1 += bf2f(u.x >> 16);
        a2 += bf2f(u.y & 0xffff); a3 += bf2f(u.y >> 16);
        a4 += bf2f(u.z & 0xffff); a5 += bf2f(u.z >> 16);
        a6 += bf2f(u.w & 0xffff); a7 += bf2f(u.w >> 16);
    }
    float sc = inv[node];
    uint4 r;
    r.x = (unsigned)f2bf(a0 * sc) | ((unsigned)f2bf(a1 * sc) << 16);
    r.y = (unsigned)f2bf(a2 * sc) | ((unsigned)f2bf(a3 * sc) << 16);
    r.z = (unsigned)f2bf(a4 * sc) | ((unsigned)f2bf(a5 * sc) << 16);
    r.w = (unsigned)f2bf(a6 * sc) | ((unsigned)f2bf(a7 * sc) << 16);
    reinterpret_cast<uint4*>(agg)[node * 16 + c] = r;
}

// layer-2 fused: out[node] = inv * sum_{src} p[src] + q[node]  (p,q f32 16-wide)
__global__ __launch_bounds__(256) void gather2_kernel(
    const float* __restrict__ pq, const int* __restrict__ offs,
    const int* __restrict__ ebuf, const float* __restrict__ inv,
    float* __restrict__ out)
{
    int t = blockIdx.x * blockDim.x + threadIdx.x;
    int node = t >> 2;
    int c = t & 3;
    if (node >= NNODES) return;
    int beg = offs[node];
    int end = offs[node + 1];
    float ax = 0.f, ay = 0.f, az = 0.f, aw = 0.f;
    int j = beg;
    for (; j + 1 < end; j += 2) {
        int s0 = ebuf[j], s1 = ebuf[j + 1];
        float4 v0 = reinterpret_cast<const float4*>(pq)[s0 * 8 + c];
        float4 v1 = reinterpret_cast<const float4*>(pq)[s1 * 8 + c];
        ax += v0.x + v1.x; ay += v0.y + v1.y; az += v0.z + v1.z; aw += v0.w + v1.w;
    }
    if (j < end) {
        int s0 = ebuf[j];
        float4 v0 = reinterpret_cast<const float4*>(pq)[s0 * 8 + c];
        ax += v0.x; ay += v0.y; az += v0.z; aw += v0.w;
    }
    float sc = inv[node];
    float4 q = reinterpret_cast<const float4*>(pq)[node * 8 + 4 + c];
    float4 r;
    r.x = ax * sc + q.x; r.y = ay * sc + q.y; r.z = az * sc + q.z; r.w = aw * sc + q.w;
    reinterpret_cast<float4*>(out)[node * 4 + c] = r;
}

// h[row][col] = relu( [agg | xb](row,:) @ [W1l;W1r](:,colbase+col) + b1[col] ), bf16 out
__global__ __launch_bounds__(256) void gemm1_kernel(
    const unsigned short* __restrict__ agg, const unsigned short* __restrict__ xb,
    const float* __restrict__ Wl, const float* __restrict__ Wr,
    const float* __restrict__ bias, unsigned short* __restrict__ out, int ntiles)
{
    constexpr int NCOL = 64;
    __shared__ alignas(16) unsigned short At[64 * 256];
    __shared__ alignas(16) unsigned short Wt[NCOL * 256];

    const int tid = threadIdx.x;
    const int colbase = blockIdx.y * NCOL;

    for (int idx = tid; idx < 128 * NCOL; idx += 256) {
        int k = idx / NCOL;
        int n = idx % NCOL;
        float vl = Wl[k * HDIM + colbase + n];
        float vr = Wr[k * HDIM + colbase + n];
        int ck = k >> 3;
        Wt[n * 256 + ((ck ^ (n & 7)) << 3) + (k & 7)] = f2bf(vl);
        int ck2 = (k + 128) >> 3;
        Wt[n * 256 + ((ck2 ^ (n & 7)) << 3) + (k & 7)] = f2bf(vr);
    }

    const int wave = tid >> 6;
    const int lane = tid & 63;
    const int lm = lane & 15;
    const int lq = lane >> 4;

    for (int tile = blockIdx.x; tile < ntiles; tile += gridDim.x) {
        int row0 = tile * 64;
        __syncthreads();

        #pragma unroll
        for (int i = 0; i < 4; ++i) {
            int idx = tid + i * 256;
            int r = idx >> 4;
            int ch = idx & 15;
            int row = row0 + r;
            uint4 v = make_uint4(0u, 0u, 0u, 0u);
            if (row < NNODES) v = reinterpret_cast<const uint4*>(agg)[(size_t)row * 16 + ch];
            *reinterpret_cast<uint4*>(&At[r * 256 + ((ch ^ (r & 7)) << 3)]) = v;
        }
        #pragma unroll
        for (int i = 0; i < 4; ++i) {
            int idx = tid + i * 256;
            int r = idx >> 4;
            int ch = idx & 15;
            int row = row0 + r;
            uint4 v = make_uint4(0u, 0u, 0u, 0u);
            if (row < NNODES) v = reinterpret_cast<const uint4*>(xb)[(size_t)row * 16 + ch];
            int ck = 16 + ch;
            *reinterpret_cast<uint4*>(&At[r * 256 + ((ck ^ (r & 7)) << 3)]) = v;
        }
        __syncthreads();

        constexpr int CT = NCOL / 16;
        f32x4 acc[CT];
        #pragma unroll
        for (int c = 0; c < CT; ++c) acc[c] = (f32x4)(0.0f);

        const int arow = wave * 16 + lm;
        const int arh = arow & 7;
        #pragma unroll
        for (int kt = 0; kt < 8; ++kt) {
            int c = kt * 4 + lq;
            bf16x8 a = *reinterpret_cast<const bf16x8*>(&At[arow * 256 + ((c ^ arh) << 3)]);
            #pragma unroll
            for (int ct = 0; ct < CT; ++ct) {
                int n = ct * 16 + lm;
                bf16x8 b = *reinterpret_cast<const bf16x8*>(&Wt[n * 256 + ((c ^ (n & 7)) << 3)]);
                acc[ct] = __builtin_amdgcn_mfma_f32_16x16x32_bf16(a, b, acc[ct], 0, 0, 0);
            }
        }

        #pragma unroll
        for (int ct = 0; ct < CT; ++ct) {
            int col = colbase + ct * 16 + lm;
            float bv = bias[col];
            #pragma unroll
            for (int i = 0; i < 4; ++i) {
                int row = row0 + wave * 16 + lq * 4 + i;
                if (row < NNODES) {
                    float v = fmaxf(acc[ct][i] + bv, 0.0f);
                    out[(size_t)row * HDIM + col] = f2bf(v);
                }
            }
        }
    }
}

// pq[row][0:16]=h@W2l (p), pq[row][16:32]=h@W2r+b2 (q). K=128, f32 out.
__global__ __launch_bounds__(256) void gemm2_kernel(
    const unsigned short* __restrict__ h, const float* __restrict__ Wl,
    const float* __restrict__ Wr, const float* __restrict__ bias,
    float* __restrict__ pq, int ntiles)
{
    __shared__ alignas(16) unsigned short At[64 * 128];
    __shared__ alignas(16) unsigned short Wt[32 * 128];

    const int tid = threadIdx.x;

    for (int idx = tid; idx < 128 * 32; idx += 256) {
        int k = idx >> 5;
        int n = idx & 31;
        float v = (n < 16) ? Wl[k * CDIM + n] : Wr[k * CDIM + (n - 16)];
        int ck = k >> 3;
        Wt[n * 128 + ((ck ^ (n & 7)) << 3) + (k & 7)] = f2bf(v);
    }

    const int wave = tid >> 6;
    const int lane = tid & 63;
    const int lm = lane & 15;
    const int lq = lane >> 4;

    for (int tile = blockIdx.x; tile < ntiles; tile += gridDim.x) {
        int row0 = tile * 64;
        __syncthreads();

        #pragma unroll
        for (int i = 0; i < 4; ++i) {
            int idx = tid + i * 256;
            int r = idx >> 4;
            int ch = idx & 15;
            int row = row0 + r;
            uint4 v = make_uint4(0u, 0u, 0u, 0u);
            if (row < NNODES) v = reinterpret_cast<const uint4*>(h)[(size_t)row * 16 + ch];
            *reinterpret_cast<uint4*>(&At[r * 128 + ((ch ^ (r & 7)) << 3)]) = v;
        }
        __syncthreads();

        f32x4 acc[2];
        acc[0] = (f32x4)(0.0f);
        acc[1] = (f32x4)(0.0f);

        const int arow = wave * 16 + lm;
        const int arh = arow & 7;
        #pragma unroll
        for (int kt = 0; kt < 4; ++kt) {
            int c = kt * 4 + lq;
            bf16x8 a = *reinterpret_cast<const bf16x8*>(&At[arow * 128 + ((c ^ arh) << 3)]);
            #pragma unroll
            for (int ct = 0; ct < 2; ++ct) {
                int n = ct * 16 + lm;
                bf16x8 b = *reinterpret_cast<const bf16x8*>(&Wt[n * 128 + ((c ^ (n & 7)) << 3)]);
                acc[ct] = __builtin_amdgcn_mfma_f32_16x16x32_bf16(a, b, acc[ct], 0, 0, 0);
            }
        }

        #pragma unroll
        for (int ct = 0; ct < 2; ++ct) {
            int col = ct * 16 + lm;
            float bv = (ct == 1) ? bias[lm] : 0.0f;
            #pragma unroll
            for (int i = 0; i < 4; ++i) {
                int row = row0 + wave * 16 + lq * 4 + i;
                if (row < NNODES)
                    pq[(size_t)row * 32 + col] = acc[ct][i] + bv;
            }
        }
    }
}

extern "C" void kernel_launch(void* const* d_in, const int* in_sizes, int n_in,
                              void* d_out, int out_size, void* d_ws, size_t ws_size,
                              hipStream_t stream) {
    const float* x   = (const float*)d_in[0];
    const int*   ei  = (const int*)d_in[1];
    const float* W1l = (const float*)d_in[2];
    const float* W1r = (const float*)d_in[3];
    const float* b1  = (const float*)d_in[4];
    const float* W2l = (const float*)d_in[5];
    const float* W2r = (const float*)d_in[6];
    const float* b2  = (const float*)d_in[7];
    float* out = (float*)d_out;

    const int* src = ei;
    const int* dst = ei + NEDGES;

    // workspace layout
    int* cnt_inv = (int*)d_ws;                      // NP ints
    int* offs    = cnt_inv + NP;                    // NP ints
    int* cursor  = offs + NP;                       // NP ints
    int* bsum    = cursor + NP;                     // 128 ints
    int* ebuf    = bsum + 128;                      // E ints
    unsigned short* xb  = (unsigned short*)(ebuf + ((NEDGES + 3) & ~3));   // N*128 bf16
    unsigned short* agg = xb + (size_t)NNODES * HDIM;                      // N*128 bf16
    unsigned short* h   = agg + (size_t)NNODES * HDIM;                     // N*128 bf16
    float* pq = (float*)(h + (size_t)NNODES * HDIM);                       // N*32 f32

    hipMemsetAsync(cnt_inv, 0, NP * sizeof(int), stream);

    cvt_kernel<<<(NNODES * 32 + 255) / 256, 256, 0, stream>>>(x, xb);
    hist_kernel<<<(NEDGES + 255) / 256, 256, 0, stream>>>(dst, cnt_inv);
    bsum_kernel<<<NP / 1024, 256, 0, stream>>>(cnt_inv, bsum);
    bscan_kernel<<<1, 128, 0, stream>>>(bsum);
    offs_kernel<<<NP / 1024, 256, 0, stream>>>(cnt_inv, bsum, offs, cursor);
    bin_kernel<<<(NEDGES + 255) / 256, 256, 0, stream>>>(src, dst, cursor, ebuf);

    const float* inv = (const float*)cnt_inv;
    int ntiles = (NNODES + 63) / 64;

    // layer 1
    gather1_kernel<<<(NNODES * 16 + 255) / 256, 256, 0, stream>>>(xb, offs, ebuf, inv, agg);
    gemm1_kernel<<<dim3(256, 2), 256, 0, stream>>>(agg, xb, W1l, W1r, b1, h, ntiles);

    // layer 2
    gemm2_kernel<<<512, 256, 0, stream>>>(h, W2l, W2r, b2, pq, ntiles);
    gather2_kernel<<<(NNODES * 4 + 255) / 256, 256, 0, stream>>>(pq, offs, ebuf, inv, out);
}